// Round 1
// baseline (581.490 us; speedup 1.0000x reference)
//
#include <hip/hip_runtime.h>
#include <hip/hip_bf16.h>
#include <math.h>

#define Bn 4
#define Nn 2048
#define FIN 128
#define Hh 4
#define HIDn 32
#define En 4
#define ISPLIT 8

typedef __bf16 bf16x8 __attribute__((ext_vector_type(8)));
typedef float  f32x4  __attribute__((ext_vector_type(4)));

// K1: ht = h @ W  (B,N,128); emit htT bf16 [b][h][hid][n], s_i/s_j fp32 [b][h][n]
__global__ __launch_bounds__(256) void k1_proj(const float* __restrict__ h,
    const float* __restrict__ W, const float* __restrict__ a,
    __bf16* __restrict__ htT, float* __restrict__ s_i, float* __restrict__ s_j)
{
    __shared__ float hl[16][FIN];
    const int b  = blockIdx.y;
    const int n0 = blockIdx.x * 16;
    const int t  = threadIdx.x;
    for (int k = t; k < 16 * FIN; k += 256) {
        int r = k >> 7, f = k & 127;
        hl[r][f] = h[((size_t)(b * Nn + n0 + r)) * FIN + f];
    }
    __syncthreads();
    const int d   = t & 127;
    const int ng  = t >> 7;
    const int hh  = d >> 5;
    const int hid = d & 31;
    float acc[8];
#pragma unroll
    for (int r = 0; r < 8; r++) acc[r] = 0.f;
    for (int f = 0; f < FIN; f++) {
        float wv = W[f * 128 + d];
#pragma unroll
        for (int r = 0; r < 8; r++) acc[r] = fmaf(hl[ng * 8 + r][f], wv, acc[r]);
    }
    const float ai = a[hh * 68 + hid];
    const float aj = a[hh * 68 + 32 + hid];
#pragma unroll
    for (int r = 0; r < 8; r++) {
        float vi = acc[r] * ai;
        float vj = acc[r] * aj;
#pragma unroll
        for (int m = 16; m >= 1; m >>= 1) {
            vi += __shfl_xor(vi, m, 64);
            vj += __shfl_xor(vj, m, 64);
        }
        if (hid == 0) {
            int n = n0 + ng * 8 + r;
            s_i[(b * Hh + hh) * Nn + n] = vi;
            s_j[(b * Hh + hh) * Nn + n] = vj;
        }
    }
    bf16x8 pack;
#pragma unroll
    for (int r = 0; r < 8; r++) pack[r] = (__bf16)acc[r];
    *(bf16x8*)(htT + ((size_t)((b * Hh + hh) * HIDn + hid)) * Nn + n0 + ng * 8) = pack;
}

// K2: per-column partial sums  S[b][j][h][split] = sum_i exp(beta) over unmasked i
__global__ __launch_bounds__(256) void k2_stats(const float* __restrict__ edge,
    const int* __restrict__ adj, const float* __restrict__ a,
    const float* __restrict__ s_i, const float* __restrict__ s_j,
    float* __restrict__ Spart)
{
    const int b  = blockIdx.y;
    const int j  = blockIdx.x * 256 + threadIdx.x;
    const int i0 = blockIdx.z * (Nn / ISPLIT);
    float ae[4][4];
#pragma unroll
    for (int hh = 0; hh < 4; hh++)
#pragma unroll
        for (int e = 0; e < 4; e++) ae[hh][e] = a[hh * 68 + 64 + e];
    float sj[4];
#pragma unroll
    for (int hh = 0; hh < 4; hh++) sj[hh] = s_j[(b * Hh + hh) * Nn + j];
    float S[4] = {0.f, 0.f, 0.f, 0.f};
    for (int ii = 0; ii < Nn / ISPLIT; ii++) {
        int i = i0 + ii;
        const float4 e4 = *(const float4*)(edge + (((size_t)(b * Nn + i)) * Nn + j) * En);
        const int av = adj[((size_t)(b * Nn + i)) * Nn + j];
#pragma unroll
        for (int hh = 0; hh < 4; hh++) {
            float si  = s_i[(b * Hh + hh) * Nn + i];
            float dot = e4.x * ae[hh][0] + e4.y * ae[hh][1] + e4.z * ae[hh][2] + e4.w * ae[hh][3];
            float p   = __expf(si + sj[hh] + dot);
            S[hh] += (av > 0) ? p : 0.f;
        }
    }
#pragma unroll
    for (int hh = 0; hh < 4; hh++)
        Spart[((size_t)((b * Nn + j) * Hh + hh)) * ISPLIT + blockIdx.z] = S[hh];
}

// K3: sjc[b][h][j] = s_j - log(sum of partials)
__global__ __launch_bounds__(256) void k3_reduce(const float* __restrict__ Spart,
    const float* __restrict__ s_j, float* __restrict__ sjc)
{
    int idx = blockIdx.x * 256 + threadIdx.x;  // (b*Nn + j)*Hh + h
    if (idx >= Bn * Nn * Hh) return;
    float S = 0.f;
#pragma unroll
    for (int z = 0; z < ISPLIT; z++) S += Spart[(size_t)idx * ISPLIT + z];
    int hh = idx & 3;
    int j  = (idx >> 2) & (Nn - 1);
    int b  = idx >> 13;
    float c = (S > 0.f) ? __logf(S) : 0.f;
    sjc[(b * Hh + hh) * Nn + j] = s_j[(b * Hh + hh) * Nn + j] - c;
}

// K4: out[b][i][h*32+d] = sum_j exp(s_i + sjc + edge.a_e) * ht[b][h][j][d]  (MFMA)
__global__ __launch_bounds__(256) void k4_attn(const float* __restrict__ edge,
    const int* __restrict__ adj, const float* __restrict__ a,
    const float* __restrict__ s_i, const float* __restrict__ sjc,
    const __bf16* __restrict__ htT, float* __restrict__ out)
{
    __shared__ __align__(16) __bf16 pexp[4][16][72];  // stride 72: 16B aligned rows, low-conflict b128
    __shared__ float si_l[4][16];
    __shared__ float sjc_l[4][32];
    const int b    = blockIdx.y;
    const int i0   = blockIdx.x * 16;
    const int t    = threadIdx.x;
    const int w    = t >> 6;      // wave = head
    const int lane = t & 63;
    const int quad = lane >> 4;
    const int lrow = lane & 15;

    float ae[4][4];
#pragma unroll
    for (int hh = 0; hh < 4; hh++)
#pragma unroll
        for (int e = 0; e < 4; e++) ae[hh][e] = a[hh * 68 + 64 + e];

    if (t < 64) si_l[t >> 4][t & 15] = s_i[(b * Hh + (t >> 4)) * Nn + i0 + (t & 15)];

    f32x4 acc0 = {0.f, 0.f, 0.f, 0.f};
    f32x4 acc1 = {0.f, 0.f, 0.f, 0.f};

    const int jt = t & 31;   // phase-A column within tile
    const int ib = t >> 5;   // phase-A row base (0..7)

    for (int j0 = 0; j0 < Nn; j0 += 32) {
        if (t < 128) sjc_l[t >> 5][t & 31] = sjc[(b * Hh + (t >> 5)) * Nn + j0 + (t & 31)];
        __syncthreads();  // sjc ready; previous pexp fully consumed
        // ---- phase A: P tile (16 i x 32 j x 4 h), each pair's edge read once ----
#pragma unroll
        for (int rep = 0; rep < 2; rep++) {
            const int il = ib + rep * 8;
            const size_t pairIdx = ((size_t)(b * Nn + i0 + il)) * Nn + (j0 + jt);
            const float4 e4 = *(const float4*)(edge + pairIdx * En);
            const int av = adj[pairIdx];
#pragma unroll
            for (int hh = 0; hh < 4; hh++) {
                float dot = e4.x * ae[hh][0] + e4.y * ae[hh][1] + e4.z * ae[hh][2] + e4.w * ae[hh][3];
                float p = (av > 0) ? __expf(si_l[hh][il] + sjc_l[hh][jt] + dot) : 0.f;
                pexp[hh][il][jt] = (__bf16)p;
            }
        }
        __syncthreads();
        // ---- phase B: MFMA  (A: m=lane&15,k=quad*8+j ; B from htT[d][j] ; D: col=lane&15,row=quad*4+reg)
        bf16x8 af = *(const bf16x8*)&pexp[w][lrow][quad * 8];
        const __bf16* bbase = htT + ((size_t)((b * Hh + w) * HIDn)) * Nn;
        bf16x8 bf0 = *(const bf16x8*)(bbase + (size_t)(0  + lrow) * Nn + j0 + quad * 8);
        bf16x8 bf1 = *(const bf16x8*)(bbase + (size_t)(16 + lrow) * Nn + j0 + quad * 8);
        acc0 = __builtin_amdgcn_mfma_f32_16x16x32_bf16(af, bf0, acc0, 0, 0, 0);
        acc1 = __builtin_amdgcn_mfma_f32_16x16x32_bf16(af, bf1, acc1, 0, 0, 0);
    }
#pragma unroll
    for (int r = 0; r < 4; r++) {
        const int i = i0 + quad * 4 + r;
        out[((size_t)(b * Nn + i)) * 128 + w * 32 + 0  + lrow] = acc0[r];
        out[((size_t)(b * Nn + i)) * 128 + w * 32 + 16 + lrow] = acc1[r];
    }
}

extern "C" void kernel_launch(void* const* d_in, const int* in_sizes, int n_in,
                              void* d_out, int out_size, void* d_ws, size_t ws_size,
                              hipStream_t stream)
{
    const float* h    = (const float*)d_in[0];
    const int*   adj  = (const int*)d_in[1];
    const float* edge = (const float*)d_in[2];
    const float* W    = (const float*)d_in[3];
    const float* a    = (const float*)d_in[4];
    float* out = (float*)d_out;

    char* ws = (char*)d_ws;
    __bf16* htT  = (__bf16*)(ws);                 // 2,097,152 B
    float*  s_i  = (float*)(ws + 2097152);        //   131,072 B
    float*  s_j  = (float*)(ws + 2228224);        //   131,072 B
    float*  sjc  = (float*)(ws + 2359296);        //   131,072 B
    float*  Spart= (float*)(ws + 2490368);        // 1,048,576 B  (total ~3.4 MB)

    k1_proj  <<<dim3(Nn / 16, Bn),        256, 0, stream>>>(h, W, a, htT, s_i, s_j);
    k2_stats <<<dim3(Nn / 256, Bn, ISPLIT), 256, 0, stream>>>(edge, adj, a, s_i, s_j, Spart);
    k3_reduce<<<dim3((Bn * Nn * Hh) / 256), 256, 0, stream>>>(Spart, s_j, sjc);
    k4_attn  <<<dim3(Nn / 16, Bn),        256, 0, stream>>>(edge, adj, a, s_i, sjc, htT, out);
}

// Round 2
// 517.274 us; speedup vs baseline: 1.1241x; 1.1241x over previous
//
#include <hip/hip_runtime.h>
#include <hip/hip_bf16.h>
#include <math.h>

#define Bn 4
#define Nn 2048
#define FIN 128
#define Hh 4
#define HIDn 32
#define En 4
#define ZS 32            // i-splits in pass 1
#define RPT (Nn / ZS)    // 64 rows per thread

typedef __bf16 bf16x8 __attribute__((ext_vector_type(8)));
typedef float  f32x4  __attribute__((ext_vector_type(4)));

// K1: ht = h @ W  (B,N,128); emit htT bf16 [b][h][hid][n], s_i/s_j fp32 [b][h][n]
__global__ __launch_bounds__(256) void k1_proj(const float* __restrict__ h,
    const float* __restrict__ W, const float* __restrict__ a,
    __bf16* __restrict__ htT, float* __restrict__ s_i, float* __restrict__ s_j)
{
    __shared__ float hl[16][FIN];
    const int b  = blockIdx.y;
    const int n0 = blockIdx.x * 16;
    const int t  = threadIdx.x;
    for (int k = t; k < 16 * FIN; k += 256) {
        int r = k >> 7, f = k & 127;
        hl[r][f] = h[((size_t)(b * Nn + n0 + r)) * FIN + f];
    }
    __syncthreads();
    const int d   = t & 127;
    const int ng  = t >> 7;
    const int hh  = d >> 5;
    const int hid = d & 31;
    float acc[8];
#pragma unroll
    for (int r = 0; r < 8; r++) acc[r] = 0.f;
    for (int f = 0; f < FIN; f++) {
        float wv = W[f * 128 + d];
#pragma unroll
        for (int r = 0; r < 8; r++) acc[r] = fmaf(hl[ng * 8 + r][f], wv, acc[r]);
    }
    const float ai = a[hh * 68 + hid];
    const float aj = a[hh * 68 + 32 + hid];
#pragma unroll
    for (int r = 0; r < 8; r++) {
        float vi = acc[r] * ai;
        float vj = acc[r] * aj;
#pragma unroll
        for (int m = 16; m >= 1; m >>= 1) {
            vi += __shfl_xor(vi, m, 64);
            vj += __shfl_xor(vj, m, 64);
        }
        if (hid == 0) {
            int n = n0 + ng * 8 + r;
            s_i[(b * Hh + hh) * Nn + n] = vi;
            s_j[(b * Hh + hh) * Nn + n] = vj;
        }
    }
    bf16x8 pack;
#pragma unroll
    for (int r = 0; r < 8; r++) pack[r] = (__bf16)acc[r];
    *(bf16x8*)(htT + ((size_t)((b * Hh + hh) * HIDn + hid)) * Nn + n0 + ng * 8) = pack;
}

// K2: P[b][h][i][j] = adj ? exp(s_i + s_j + edge.a_e) : 0  (bf16, unnormalized)
//     Dpart[b][h][z][j] = partial column sums over this block's i-range
__global__ __launch_bounds__(256) void k2_pexp(const float* __restrict__ edge,
    const int* __restrict__ adj, const float* __restrict__ a,
    const float* __restrict__ s_i, const float* __restrict__ s_j,
    __bf16* __restrict__ P, float* __restrict__ Dpart)
{
    __shared__ float si_l[4][RPT];
    const int b  = blockIdx.y;
    const int z  = blockIdx.z;
    const int i0 = z * RPT;
    const int t  = threadIdx.x;
    const int j  = blockIdx.x * 256 + t;
    // stage s_i for this i-range (4 heads x 64 rows = 256 values)
    si_l[t >> 6][t & 63] = s_i[(b * Hh + (t >> 6)) * Nn + i0 + (t & 63)];
    float ae[4][4];
#pragma unroll
    for (int hh = 0; hh < 4; hh++)
#pragma unroll
        for (int e = 0; e < 4; e++) ae[hh][e] = a[hh * 68 + 64 + e];
    float sj[4];
#pragma unroll
    for (int hh = 0; hh < 4; hh++) sj[hh] = s_j[(b * Hh + hh) * Nn + j];
    __syncthreads();
    float D[4] = {0.f, 0.f, 0.f, 0.f};
#pragma unroll 2
    for (int ii = 0; ii < RPT; ii++) {
        const int i = i0 + ii;
        const size_t pr = ((size_t)(b * Nn + i)) * Nn + j;
        const float4 e4 = *(const float4*)(edge + pr * En);
        const int av = adj[pr];
#pragma unroll
        for (int hh = 0; hh < 4; hh++) {
            float dot = e4.x * ae[hh][0] + e4.y * ae[hh][1] + e4.z * ae[hh][2] + e4.w * ae[hh][3];
            float p = (av > 0) ? __expf(si_l[hh][ii] + sj[hh] + dot) : 0.f;
            D[hh] += p;
            P[((size_t)((b * Hh + hh) * Nn + i)) * Nn + j] = (__bf16)p;
        }
    }
#pragma unroll
    for (int hh = 0; hh < 4; hh++)
        Dpart[((size_t)((b * Hh + hh) * ZS + z)) * Nn + j] = D[hh];
}

// K3: htD[bh][d][j] = htT[bh][d][j] / D_j   (folds softmax denominator into B-operand)
__global__ __launch_bounds__(256) void k3_scale(const float* __restrict__ Dpart,
    const __bf16* __restrict__ htT, __bf16* __restrict__ htD)
{
    const int idx = blockIdx.x * 256 + threadIdx.x;  // bh*Nn + j
    const int j   = idx & (Nn - 1);
    const int bh  = idx >> 11;
    float S = 0.f;
#pragma unroll
    for (int z = 0; z < ZS; z++) S += Dpart[((size_t)(bh * ZS + z)) * Nn + j];
    const float r = (S > 0.f) ? 1.f / S : 0.f;
#pragma unroll
    for (int d = 0; d < HIDn; d++) {
        const size_t o = ((size_t)(bh * HIDn + d)) * Nn + j;
        htD[o] = (__bf16)((float)htT[o] * r);
    }
}

// K4: out[b][i][h*32+d] = sum_j P[bh][i][j] * htD[bh][d][j]   (pure bf16 GEMM, no LDS)
__global__ __launch_bounds__(256) void k4_gemm(const __bf16* __restrict__ P,
    const __bf16* __restrict__ htD, float* __restrict__ out)
{
    const int bh   = blockIdx.y;
    const int t    = threadIdx.x;
    const int w    = t >> 6;
    const int lane = t & 63;
    const int quad = lane >> 4;
    const int lrow = lane & 15;
    const int i0   = blockIdx.x * 64 + w * 16;

    const __bf16* Arow = P   + (size_t)bh * Nn * Nn + (size_t)(i0 + lrow) * Nn + quad * 8;
    const __bf16* B0   = htD + (size_t)bh * HIDn * Nn + (size_t)lrow * Nn + quad * 8;
    const __bf16* B1   = B0 + (size_t)16 * Nn;

    f32x4 acc0 = {0.f, 0.f, 0.f, 0.f};
    f32x4 acc1 = {0.f, 0.f, 0.f, 0.f};
#pragma unroll 4
    for (int k0 = 0; k0 < Nn; k0 += 32) {
        bf16x8 af = *(const bf16x8*)(Arow + k0);
        bf16x8 b0 = *(const bf16x8*)(B0 + k0);
        bf16x8 b1 = *(const bf16x8*)(B1 + k0);
        acc0 = __builtin_amdgcn_mfma_f32_16x16x32_bf16(af, b0, acc0, 0, 0, 0);
        acc1 = __builtin_amdgcn_mfma_f32_16x16x32_bf16(af, b1, acc1, 0, 0, 0);
    }
    const int b = bh >> 2, hh = bh & 3;
#pragma unroll
    for (int r = 0; r < 4; r++) {
        const int i = i0 + quad * 4 + r;
        out[((size_t)(b * Nn + i)) * 128 + hh * 32 + 0  + lrow] = acc0[r];
        out[((size_t)(b * Nn + i)) * 128 + hh * 32 + 16 + lrow] = acc1[r];
    }
}

extern "C" void kernel_launch(void* const* d_in, const int* in_sizes, int n_in,
                              void* d_out, int out_size, void* d_ws, size_t ws_size,
                              hipStream_t stream)
{
    const float* h    = (const float*)d_in[0];
    const int*   adj  = (const int*)d_in[1];
    const float* edge = (const float*)d_in[2];
    const float* W    = (const float*)d_in[3];
    const float* a    = (const float*)d_in[4];
    float* out = (float*)d_out;

    char* ws = (char*)d_ws;
    __bf16* htT   = (__bf16*)(ws);                   //  2,097,152 B
    __bf16* htD   = (__bf16*)(ws + 2097152);         //  2,097,152 B
    float*  s_i   = (float*)(ws + 4194304);          //    131,072 B
    float*  s_j   = (float*)(ws + 4325376);          //    131,072 B
    float*  Dpart = (float*)(ws + 4456448);          // 16,777,216 B
    __bf16* P     = (__bf16*)(ws + 21233664);        // 134,217,728 B  (total ~155 MB)

    k1_proj <<<dim3(Nn / 16, Bn),      256, 0, stream>>>(h, W, a, htT, s_i, s_j);
    k2_pexp <<<dim3(Nn / 256, Bn, ZS), 256, 0, stream>>>(edge, adj, a, s_i, s_j, P, Dpart);
    k3_scale<<<dim3(Bn * Hh * Nn / 256), 256, 0, stream>>>(Dpart, htT, htD);
    k4_gemm <<<dim3(Nn / 64, Bn * Hh), 256, 0, stream>>>(P, htD, out);
}